// Round 3
// baseline (318.449 us; speedup 1.0000x reference)
//
#include <hip/hip_runtime.h>

#define HW_  (128*240)   // 30720
#define W_   240
#define H_   128
#define B_   4
#define C_   32
#define J_   15
#define TILE 120         // HW_/TILE = 256 tiles -> 1024 blocks = exactly 4/CU
#define NT_  256
#define NSLOT (TILE*35/4)   // 1050 float4 slots per tile
#define JSTRIDE ((size_t)B_*HW_*35)  // out elements between j-slices
#define WS_PER_B 21      // [0..8] Kinv, [9..20] T rows 0..2 (3x4 row-major)

typedef float vfloat4 __attribute__((ext_vector_type(4)));  // native clang vector

__global__ void setup_kernel(const float* __restrict__ K,
                             const float* __restrict__ M,
                             const float* __restrict__ trans,
                             float* __restrict__ ws) {
    int b = threadIdx.x;
    if (b >= B_) return;

    // ---- invert K (3x3), Gauss-Jordan w/ partial pivoting ----
    float a[3][6];
    for (int i = 0; i < 3; i++) {
        for (int j = 0; j < 3; j++) {
            a[i][j]     = K[b * 9 + i * 3 + j];
            a[i][3 + j] = (i == j) ? 1.0f : 0.0f;
        }
    }
    for (int col = 0; col < 3; col++) {
        int piv = col; float mx = fabsf(a[col][col]);
        for (int r = col + 1; r < 3; r++) {
            float v = fabsf(a[r][col]);
            if (v > mx) { mx = v; piv = r; }
        }
        if (piv != col) {
            for (int j = 0; j < 6; j++) { float t = a[col][j]; a[col][j] = a[piv][j]; a[piv][j] = t; }
        }
        float inv = 1.0f / a[col][col];
        for (int j = 0; j < 6; j++) a[col][j] *= inv;
        for (int r = 0; r < 3; r++) {
            if (r == col) continue;
            float f = a[r][col];
            for (int j = 0; j < 6; j++) a[r][j] -= f * a[col][j];
        }
    }
    for (int i = 0; i < 3; i++)
        for (int j = 0; j < 3; j++)
            ws[b * WS_PER_B + i * 3 + j] = a[i][3 + j];

    // ---- invert M (4x4), Gauss-Jordan w/ partial pivoting ----
    float m[4][8];
    for (int i = 0; i < 4; i++) {
        for (int j = 0; j < 4; j++) {
            m[i][j]     = M[b * 16 + i * 4 + j];
            m[i][4 + j] = (i == j) ? 1.0f : 0.0f;
        }
    }
    for (int col = 0; col < 4; col++) {
        int piv = col; float mx = fabsf(m[col][col]);
        for (int r = col + 1; r < 4; r++) {
            float v = fabsf(m[r][col]);
            if (v > mx) { mx = v; piv = r; }
        }
        if (piv != col) {
            for (int j = 0; j < 8; j++) { float t = m[col][j]; m[col][j] = m[piv][j]; m[piv][j] = t; }
        }
        float inv = 1.0f / m[col][col];
        for (int j = 0; j < 8; j++) m[col][j] *= inv;
        for (int r = 0; r < 4; r++) {
            if (r == col) continue;
            float f = m[r][col];
            for (int j = 0; j < 8; j++) m[r][j] -= f * m[col][j];
        }
    }
    // ---- T = trans @ Minv, keep rows 0..2 ----
    for (int i = 0; i < 3; i++) {
        for (int k = 0; k < 4; k++) {
            float s = trans[b * 16 + i * 4 + 0] * m[0][4 + k];
            s += trans[b * 16 + i * 4 + 1] * m[1][4 + k];
            s += trans[b * 16 + i * 4 + 2] * m[2][4 + k];
            s += trans[b * 16 + i * 4 + 3] * m[3][4 + k];
            ws[b * WS_PER_B + 9 + i * 4 + k] = s;
        }
    }
}

__global__ __launch_bounds__(NT_) void points_kernel(
    const float* __restrict__ dep,
    const int*   __restrict__ mask,
    const float* __restrict__ feat,
    const float* __restrict__ diff,
    const float* __restrict__ ws,
    const int*   __restrict__ origW,
    const int*   __restrict__ origH,
    float*       __restrict__ out)
{
    __shared__ __align__(16) float pc_s[TILE * 35];  // tile in flat output layout
    __shared__ int bits_s[TILE + 1];                 // 15 mask bits per point

    const int b   = blockIdx.y;
    const int p0  = blockIdx.x * TILE;
    const int tid = threadIdx.x;

    // ---- stage features: pc_s[pl*35 + 3 + c], coalesced global reads ----
    const float* fbase = feat + (size_t)b * C_ * HW_ + p0;
    for (int idx = tid; idx < C_ * TILE; idx += NT_) {
        int c  = idx / TILE;            // const div -> magic mul
        int pl = idx - c * TILE;
        pc_s[pl * 35 + 3 + c] = fbase[(size_t)c * HW_ + pl];
    }
    // ---- stage masks bit-packed + geometry (threads 0..TILE-1) ----
    if (tid < TILE) {
        const int* mbase = mask + (size_t)b * HW_ + p0 + tid;
        int bits = 0;
        #pragma unroll
        for (int j = 0; j < J_; j++)
            bits |= (mbase[(size_t)j * B_ * HW_] & 1) << j;
        bits_s[tid] = bits;

        const float* w = ws + b * WS_PER_B;
        const float k00 = w[0], k01 = w[1], k02 = w[2];
        const float k10 = w[3], k11 = w[4], k12 = w[5];
        const float sW = (float)origW[0] / 480.0f;    // 4.0 exact
        const float sH = (float)origH[0] / (float)H_; // 8.4375 exact

        int p  = p0 + tid;
        int hh = p / W_;
        int wi = p - hh * W_;
        float x = ((float)wi + 71.0f) * sW;
        float y = (float)hh * sH;

        float x_bak = k00 * x + k01 * y + k02;
        float y_bak = k10 * x + k11 * y + k12;

        const float* d = diff + b * 12;
        float d0 = d[0], d1 = d[1], d2 = d[2], d3 = d[3], d4 = d[4], d5 = d[5];
        float d6 = d[6], d7 = d[7], d8 = d[8], d9 = d[9], d10 = d[10], d11 = d[11];

        float xd = x_bak, yd = y_bak;
        #pragma unroll
        for (int it = 0; it < 5; it++) {
            float r2  = xd * xd + yd * yd;
            float num = 1.0f + ((d7 * r2 + d6) * r2 + d5) * r2;
            float den = 1.0f + ((d4 * r2 + d1) * r2 + d0) * r2;
            float icd = num / den;
            float dX = 2.0f * d2 * xd * yd + d3 * (r2 + 2.0f * xd * xd) + d8 * r2 + d9 * r2 * r2;
            float dY = d2 * (r2 + 2.0f * yd * yd) + 2.0f * d3 * xd * yd + d10 * r2 + d11 * r2 * r2;
            xd = (x_bak - dX) * icd;
            yd = (y_bak - dY) * icd;
        }
        float depth = dep[(size_t)b * HW_ + p];
        xd *= depth;
        yd *= depth;
        const float* T = w + 9;
        pc_s[tid * 35 + 0] = T[0] * xd + T[1] * yd + T[2]  * depth + T[3];
        pc_s[tid * 35 + 1] = T[4] * xd + T[5] * yd + T[6]  * depth + T[7];
        pc_s[tid * 35 + 2] = T[8] * xd + T[9] * yd + T[10] * depth + T[11];
    }
    __syncthreads();

    // ---- write phase: read each float4 + mask bits ONCE, store 15 j-slices ----
    float* base0 = out + (size_t)b * HW_ * 35 + (size_t)p0 * 35;
    for (int i4 = tid; i4 < NSLOT; i4 += NT_) {
        int e   = i4 << 2;
        int pA  = e / 35;                 // magic mul
        int rem = e - pA * 35;
        int r   = 35 - rem;               // components belonging to point pA (>=1; ==4 at tile end)
        vfloat4 v = *((const vfloat4*)&pc_s[e]);
        int bitsA = bits_s[pA];
        int bitsB = bits_s[pA + 1];       // unused when r>=4; in-bounds (r>=4 at pA==TILE-1)
        int b0 = bitsA;
        int b1 = (r > 1) ? bitsA : bitsB;
        int b2 = (r > 2) ? bitsA : bitsB;
        int b3 = (r > 3) ? bitsA : bitsB;
        float* dst = base0 + e;
        #pragma unroll
        for (int j = 0; j < J_; j++) {
            vfloat4 o;
            o.x = ((b0 >> j) & 1) ? v.x : 0.0f;
            o.y = ((b1 >> j) & 1) ? v.y : 0.0f;
            o.z = ((b2 >> j) & 1) ? v.z : 0.0f;
            o.w = ((b3 >> j) & 1) ? v.w : 0.0f;
            __builtin_nontemporal_store(o, (vfloat4*)(dst + (size_t)j * JSTRIDE));
        }
    }
}

extern "C" void kernel_launch(void* const* d_in, const int* in_sizes, int n_in,
                              void* d_out, int out_size, void* d_ws, size_t ws_size,
                              hipStream_t stream) {
    const float* dep   = (const float*)d_in[0];  // pred_depth  [B,1,H,W]
    const int*   maskp = (const int*)  d_in[1];  // filter_mask [J,B,H,W]
    const float* K     = (const float*)d_in[2];  // K_matrix    [B,3,3]
    const float* M     = (const float*)d_in[3];  // M_matrix    [B,4,4]
    const float* diff  = (const float*)d_in[4];  // diff        [B,12]
    const float* trans = (const float*)d_in[5];  // trans_matrix[B,4,4]
    const float* feat  = (const float*)d_in[6];  // feature     [B,C,H,W]
    const int*   oW    = (const int*)  d_in[7];  // orig_W scalar
    const int*   oH    = (const int*)  d_in[8];  // orig_H scalar
    float* out = (float*)d_out;
    float* ws  = (float*)d_ws;

    setup_kernel<<<1, 64, 0, stream>>>(K, M, trans, ws);

    dim3 grid(HW_ / TILE, B_);   // 256 x 4 = 1024 blocks = exactly 4/CU
    points_kernel<<<grid, NT_, 0, stream>>>(dep, maskp, feat, diff, ws, oW, oH, out);
}

// Round 4
// 299.119 us; speedup vs baseline: 1.0646x; 1.0646x over previous
//
#include <hip/hip_runtime.h>

#define HW_  (128*240)   // 30720
#define W_   240
#define H_   128
#define B_   4
#define C_   32
#define J_   15
#define TILE 128         // 240 tiles x 4 = 960 blocks; tile base = 17920 B (512B-aligned)
#define NT_  256
#define NSLOT (TILE*35/4)   // 1120 float4 slots per tile
#define JSTRIDE ((size_t)B_*HW_*35)  // out elements between j-slices
#define WS_PER_B 21      // [0..8] Kinv, [9..20] T rows 0..2 (3x4 row-major)

typedef float vfloat4 __attribute__((ext_vector_type(4)));  // native clang vector

__global__ void setup_kernel(const float* __restrict__ K,
                             const float* __restrict__ M,
                             const float* __restrict__ trans,
                             float* __restrict__ ws) {
    int b = threadIdx.x;
    if (b >= B_) return;

    // ---- invert K (3x3), Gauss-Jordan w/ partial pivoting ----
    float a[3][6];
    for (int i = 0; i < 3; i++) {
        for (int j = 0; j < 3; j++) {
            a[i][j]     = K[b * 9 + i * 3 + j];
            a[i][3 + j] = (i == j) ? 1.0f : 0.0f;
        }
    }
    for (int col = 0; col < 3; col++) {
        int piv = col; float mx = fabsf(a[col][col]);
        for (int r = col + 1; r < 3; r++) {
            float v = fabsf(a[r][col]);
            if (v > mx) { mx = v; piv = r; }
        }
        if (piv != col) {
            for (int j = 0; j < 6; j++) { float t = a[col][j]; a[col][j] = a[piv][j]; a[piv][j] = t; }
        }
        float inv = 1.0f / a[col][col];
        for (int j = 0; j < 6; j++) a[col][j] *= inv;
        for (int r = 0; r < 3; r++) {
            if (r == col) continue;
            float f = a[r][col];
            for (int j = 0; j < 6; j++) a[r][j] -= f * a[col][j];
        }
    }
    for (int i = 0; i < 3; i++)
        for (int j = 0; j < 3; j++)
            ws[b * WS_PER_B + i * 3 + j] = a[i][3 + j];

    // ---- invert M (4x4), Gauss-Jordan w/ partial pivoting ----
    float m[4][8];
    for (int i = 0; i < 4; i++) {
        for (int j = 0; j < 4; j++) {
            m[i][j]     = M[b * 16 + i * 4 + j];
            m[i][4 + j] = (i == j) ? 1.0f : 0.0f;
        }
    }
    for (int col = 0; col < 4; col++) {
        int piv = col; float mx = fabsf(m[col][col]);
        for (int r = col + 1; r < 4; r++) {
            float v = fabsf(m[r][col]);
            if (v > mx) { mx = v; piv = r; }
        }
        if (piv != col) {
            for (int j = 0; j < 8; j++) { float t = m[col][j]; m[col][j] = m[piv][j]; m[piv][j] = t; }
        }
        float inv = 1.0f / m[col][col];
        for (int j = 0; j < 8; j++) m[col][j] *= inv;
        for (int r = 0; r < 4; r++) {
            if (r == col) continue;
            float f = m[r][col];
            for (int j = 0; j < 8; j++) m[r][j] -= f * m[col][j];
        }
    }
    // ---- T = trans @ Minv, keep rows 0..2 ----
    for (int i = 0; i < 3; i++) {
        for (int k = 0; k < 4; k++) {
            float s = trans[b * 16 + i * 4 + 0] * m[0][4 + k];
            s += trans[b * 16 + i * 4 + 1] * m[1][4 + k];
            s += trans[b * 16 + i * 4 + 2] * m[2][4 + k];
            s += trans[b * 16 + i * 4 + 3] * m[3][4 + k];
            ws[b * WS_PER_B + 9 + i * 4 + k] = s;
        }
    }
}

__global__ __launch_bounds__(NT_) void points_kernel(
    const float* __restrict__ dep,
    const int*   __restrict__ mask,
    const float* __restrict__ feat,
    const float* __restrict__ diff,
    const float* __restrict__ ws,
    const int*   __restrict__ origW,
    const int*   __restrict__ origH,
    float*       __restrict__ out)
{
    __shared__ __align__(16) float pc_s[TILE * 35];  // tile in flat output layout
    __shared__ int bits_s[TILE + 1];                 // 15 mask bits per point

    const int b   = blockIdx.y;
    const int p0  = blockIdx.x * TILE;
    const int tid = threadIdx.x;

    // ---- stage features: pc_s[pl*35 + 3 + c], coalesced global reads ----
    const float* fbase = feat + (size_t)b * C_ * HW_ + p0;
    for (int idx = tid; idx < C_ * TILE; idx += NT_) {
        int c  = idx >> 7;              // TILE = 128
        int pl = idx & (TILE - 1);
        pc_s[pl * 35 + 3 + c] = fbase[(size_t)c * HW_ + pl];
    }
    // ---- stage masks bit-packed + geometry (threads 0..TILE-1) ----
    if (tid < TILE) {
        const int* mbase = mask + (size_t)b * HW_ + p0 + tid;
        int bits = 0;
        #pragma unroll
        for (int j = 0; j < J_; j++)
            bits |= (mbase[(size_t)j * B_ * HW_] & 1) << j;
        bits_s[tid] = bits;

        const float* w = ws + b * WS_PER_B;
        const float k00 = w[0], k01 = w[1], k02 = w[2];
        const float k10 = w[3], k11 = w[4], k12 = w[5];
        const float sW = (float)origW[0] / 480.0f;    // 4.0 exact
        const float sH = (float)origH[0] / (float)H_; // 8.4375 exact

        int p  = p0 + tid;
        int hh = p / W_;
        int wi = p - hh * W_;
        float x = ((float)wi + 71.0f) * sW;
        float y = (float)hh * sH;

        float x_bak = k00 * x + k01 * y + k02;
        float y_bak = k10 * x + k11 * y + k12;

        const float* d = diff + b * 12;
        float d0 = d[0], d1 = d[1], d2 = d[2], d3 = d[3], d4 = d[4], d5 = d[5];
        float d6 = d[6], d7 = d[7], d8 = d[8], d9 = d[9], d10 = d[10], d11 = d[11];

        float xd = x_bak, yd = y_bak;
        #pragma unroll
        for (int it = 0; it < 5; it++) {
            float r2  = xd * xd + yd * yd;
            float num = 1.0f + ((d7 * r2 + d6) * r2 + d5) * r2;
            float den = 1.0f + ((d4 * r2 + d1) * r2 + d0) * r2;
            float icd = num / den;
            float dX = 2.0f * d2 * xd * yd + d3 * (r2 + 2.0f * xd * xd) + d8 * r2 + d9 * r2 * r2;
            float dY = d2 * (r2 + 2.0f * yd * yd) + 2.0f * d3 * xd * yd + d10 * r2 + d11 * r2 * r2;
            xd = (x_bak - dX) * icd;
            yd = (y_bak - dY) * icd;
        }
        float depth = dep[(size_t)b * HW_ + p];
        xd *= depth;
        yd *= depth;
        const float* T = w + 9;
        pc_s[tid * 35 + 0] = T[0] * xd + T[1] * yd + T[2]  * depth + T[3];
        pc_s[tid * 35 + 1] = T[4] * xd + T[5] * yd + T[6]  * depth + T[7];
        pc_s[tid * 35 + 2] = T[8] * xd + T[9] * yd + T[10] * depth + T[11];
    }
    __syncthreads();

    // ---- write phase: read each float4 + mask bits ONCE, store 15 j-slices ----
    float* base0 = out + (size_t)b * HW_ * 35 + (size_t)p0 * 35;
    for (int i4 = tid; i4 < NSLOT; i4 += NT_) {
        int e   = i4 << 2;
        int pA  = e / 35;                 // magic mul
        int rem = e - pA * 35;
        int r   = 35 - rem;               // components belonging to point pA (>=1)
        vfloat4 v = *((const vfloat4*)&pc_s[e]);
        int bitsA = bits_s[pA];
        int bitsB = bits_s[pA + 1];       // only consumed when r<4 (then pA+1 <= TILE-1)
        int b0 = bitsA;
        int b1 = (r > 1) ? bitsA : bitsB;
        int b2 = (r > 2) ? bitsA : bitsB;
        int b3 = (r > 3) ? bitsA : bitsB;
        float* dst = base0 + e;
        #pragma unroll
        for (int j = 0; j < J_; j++) {
            vfloat4 o;
            o.x = ((b0 >> j) & 1) ? v.x : 0.0f;
            o.y = ((b1 >> j) & 1) ? v.y : 0.0f;
            o.z = ((b2 >> j) & 1) ? v.z : 0.0f;
            o.w = ((b3 >> j) & 1) ? v.w : 0.0f;
            *((vfloat4*)(dst + (size_t)j * JSTRIDE)) = o;   // plain store (L2 write-combine)
        }
    }
}

extern "C" void kernel_launch(void* const* d_in, const int* in_sizes, int n_in,
                              void* d_out, int out_size, void* d_ws, size_t ws_size,
                              hipStream_t stream) {
    const float* dep   = (const float*)d_in[0];  // pred_depth  [B,1,H,W]
    const int*   maskp = (const int*)  d_in[1];  // filter_mask [J,B,H,W]
    const float* K     = (const float*)d_in[2];  // K_matrix    [B,3,3]
    const float* M     = (const float*)d_in[3];  // M_matrix    [B,4,4]
    const float* diff  = (const float*)d_in[4];  // diff        [B,12]
    const float* trans = (const float*)d_in[5];  // trans_matrix[B,4,4]
    const float* feat  = (const float*)d_in[6];  // feature     [B,C,H,W]
    const int*   oW    = (const int*)  d_in[7];  // orig_W scalar
    const int*   oH    = (const int*)  d_in[8];  // orig_H scalar
    float* out = (float*)d_out;
    float* ws  = (float*)d_ws;

    setup_kernel<<<1, 64, 0, stream>>>(K, M, trans, ws);

    dim3 grid(HW_ / TILE, B_);   // 240 x 4 = 960 blocks
    points_kernel<<<grid, NT_, 0, stream>>>(dep, maskp, feat, diff, ws, oW, oH, out);
}

// Round 5
// 293.383 us; speedup vs baseline: 1.0854x; 1.0196x over previous
//
#include <hip/hip_runtime.h>

#define HW_  (128*240)   // 30720
#define W_   240
#define H_   128
#define B_   4
#define C_   32
#define J_   15
#define TILE 128         // 240 tiles x 4 = 960 blocks; tile base = 17920 B (512B-aligned)
#define NT_  256
#define NSLOT (TILE*35/4)   // 1120 float4 slots per tile
#define JSTRIDE ((size_t)B_*HW_*35)  // out elements between j-slices

typedef float vfloat4 __attribute__((ext_vector_type(4)));  // native clang vector

__global__ __launch_bounds__(NT_) void points_kernel(
    const float* __restrict__ dep,
    const int*   __restrict__ mask,
    const float* __restrict__ feat,
    const float* __restrict__ diff,
    const float* __restrict__ K,
    const float* __restrict__ M,
    const float* __restrict__ trans,
    const int*   __restrict__ origW,
    const int*   __restrict__ origH,
    float*       __restrict__ out)
{
    __shared__ __align__(16) float pc_s[TILE * 35];  // tile in flat output layout
    __shared__ int bits_s[TILE + 1];                 // 15 mask bits per point
    __shared__ float mats_s[21];                     // [0..8] Kinv, [9..20] T (3x4)

    const int b   = blockIdx.y;
    const int p0  = blockIdx.x * TILE;
    const int tid = threadIdx.x;

    // ---- thread 0: per-batch K^-1 and T = trans @ M^-1 (divergent, ~1.5k cyc) ----
    if (tid == 0) {
        // invert K (3x3) via adjugate (K is upper-triangular-ish but do general GJ-free):
        float a[3][6];
        for (int i = 0; i < 3; i++)
            for (int j = 0; j < 3; j++) {
                a[i][j]     = K[b * 9 + i * 3 + j];
                a[i][3 + j] = (i == j) ? 1.0f : 0.0f;
            }
        for (int col = 0; col < 3; col++) {
            int piv = col; float mx = fabsf(a[col][col]);
            for (int r = col + 1; r < 3; r++) {
                float v = fabsf(a[r][col]);
                if (v > mx) { mx = v; piv = r; }
            }
            if (piv != col)
                for (int j = 0; j < 6; j++) { float t = a[col][j]; a[col][j] = a[piv][j]; a[piv][j] = t; }
            float inv = 1.0f / a[col][col];
            for (int j = 0; j < 6; j++) a[col][j] *= inv;
            for (int r = 0; r < 3; r++) {
                if (r == col) continue;
                float f = a[r][col];
                for (int j = 0; j < 6; j++) a[r][j] -= f * a[col][j];
            }
        }
        for (int i = 0; i < 3; i++)
            for (int j = 0; j < 3; j++)
                mats_s[i * 3 + j] = a[i][3 + j];

        float m[4][8];
        for (int i = 0; i < 4; i++)
            for (int j = 0; j < 4; j++) {
                m[i][j]     = M[b * 16 + i * 4 + j];
                m[i][4 + j] = (i == j) ? 1.0f : 0.0f;
            }
        for (int col = 0; col < 4; col++) {
            int piv = col; float mx = fabsf(m[col][col]);
            for (int r = col + 1; r < 4; r++) {
                float v = fabsf(m[r][col]);
                if (v > mx) { mx = v; piv = r; }
            }
            if (piv != col)
                for (int j = 0; j < 8; j++) { float t = m[col][j]; m[col][j] = m[piv][j]; m[piv][j] = t; }
            float inv = 1.0f / m[col][col];
            for (int j = 0; j < 8; j++) m[col][j] *= inv;
            for (int r = 0; r < 4; r++) {
                if (r == col) continue;
                float f = m[r][col];
                for (int j = 0; j < 8; j++) m[r][j] -= f * m[col][j];
            }
        }
        for (int i = 0; i < 3; i++)
            for (int k = 0; k < 4; k++) {
                float s = trans[b * 16 + i * 4 + 0] * m[0][4 + k]
                        + trans[b * 16 + i * 4 + 1] * m[1][4 + k]
                        + trans[b * 16 + i * 4 + 2] * m[2][4 + k]
                        + trans[b * 16 + i * 4 + 3] * m[3][4 + k];
                mats_s[9 + i * 4 + k] = s;
            }
    }

    // ---- stage features via float4 global loads: pc_s[pl*35 + 3 + c] ----
    const float* fbase = feat + (size_t)b * C_ * HW_ + p0;
    for (int idx = tid; idx < C_ * TILE / 4; idx += NT_) {   // 1024 quads, 4 iters
        int c = idx >> 5;               // TILE/4 = 32 quads per channel
        int q = idx & 31;
        vfloat4 v = *((const vfloat4*)(fbase + (size_t)c * HW_ + 4 * q));
        float* dst = &pc_s[(4 * q) * 35 + 3 + c];
        dst[0]   = v.x;
        dst[35]  = v.y;
        dst[70]  = v.z;
        dst[105] = v.w;
    }
    // ---- stage masks bit-packed (threads 0..TILE-1) ----
    if (tid < TILE) {
        const int* mbase = mask + (size_t)b * HW_ + p0 + tid;
        int bits = 0;
        #pragma unroll
        for (int j = 0; j < J_; j++)
            bits |= (mbase[(size_t)j * B_ * HW_] & 1) << j;
        bits_s[tid] = bits;
    }
    __syncthreads();

    // ---- geometry (threads 0..TILE-1), reads mats_s ----
    if (tid < TILE) {
        const float k00 = mats_s[0], k01 = mats_s[1], k02 = mats_s[2];
        const float k10 = mats_s[3], k11 = mats_s[4], k12 = mats_s[5];
        const float sW = (float)origW[0] / 480.0f;    // 4.0 exact
        const float sH = (float)origH[0] / (float)H_; // 8.4375 exact

        int p  = p0 + tid;
        int hh = p / W_;
        int wi = p - hh * W_;
        float x = ((float)wi + 71.0f) * sW;
        float y = (float)hh * sH;

        float x_bak = k00 * x + k01 * y + k02;
        float y_bak = k10 * x + k11 * y + k12;

        const float* d = diff + b * 12;
        float d0 = d[0], d1 = d[1], d2 = d[2], d3 = d[3], d4 = d[4], d5 = d[5];
        float d6 = d[6], d7 = d[7], d8 = d[8], d9 = d[9], d10 = d[10], d11 = d[11];

        float xd = x_bak, yd = y_bak;
        #pragma unroll
        for (int it = 0; it < 5; it++) {
            float r2  = xd * xd + yd * yd;
            float num = 1.0f + ((d7 * r2 + d6) * r2 + d5) * r2;
            float den = 1.0f + ((d4 * r2 + d1) * r2 + d0) * r2;
            float icd = num / den;
            float dX = 2.0f * d2 * xd * yd + d3 * (r2 + 2.0f * xd * xd) + d8 * r2 + d9 * r2 * r2;
            float dY = d2 * (r2 + 2.0f * yd * yd) + 2.0f * d3 * xd * yd + d10 * r2 + d11 * r2 * r2;
            xd = (x_bak - dX) * icd;
            yd = (y_bak - dY) * icd;
        }
        float depth = dep[(size_t)b * HW_ + p];
        xd *= depth;
        yd *= depth;
        const float* T = mats_s + 9;
        pc_s[tid * 35 + 0] = T[0] * xd + T[1] * yd + T[2]  * depth + T[3];
        pc_s[tid * 35 + 1] = T[4] * xd + T[5] * yd + T[6]  * depth + T[7];
        pc_s[tid * 35 + 2] = T[8] * xd + T[9] * yd + T[10] * depth + T[11];
    }
    __syncthreads();

    // ---- write phase: read each float4 + mask bits ONCE, store 15 j-slices ----
    float* base0 = out + (size_t)b * HW_ * 35 + (size_t)p0 * 35;
    for (int i4 = tid; i4 < NSLOT; i4 += NT_) {
        int e   = i4 << 2;
        int pA  = e / 35;                 // magic mul
        int rem = e - pA * 35;
        int r   = 35 - rem;               // components belonging to point pA (>=1)
        vfloat4 v = *((const vfloat4*)&pc_s[e]);
        int bitsA = bits_s[pA];
        int bitsB = bits_s[pA + 1];       // only consumed when r<4 (then pA+1 <= TILE-1)
        int b0 = bitsA;
        int b1 = (r > 1) ? bitsA : bitsB;
        int b2 = (r > 2) ? bitsA : bitsB;
        int b3 = (r > 3) ? bitsA : bitsB;
        float* dst = base0 + e;
        #pragma unroll
        for (int j = 0; j < J_; j++) {
            vfloat4 o;
            o.x = ((b0 >> j) & 1) ? v.x : 0.0f;
            o.y = ((b1 >> j) & 1) ? v.y : 0.0f;
            o.z = ((b2 >> j) & 1) ? v.z : 0.0f;
            o.w = ((b3 >> j) & 1) ? v.w : 0.0f;
            *((vfloat4*)(dst + (size_t)j * JSTRIDE)) = o;   // plain store (L2 write-combine)
        }
    }
}

extern "C" void kernel_launch(void* const* d_in, const int* in_sizes, int n_in,
                              void* d_out, int out_size, void* d_ws, size_t ws_size,
                              hipStream_t stream) {
    const float* dep   = (const float*)d_in[0];  // pred_depth  [B,1,H,W]
    const int*   maskp = (const int*)  d_in[1];  // filter_mask [J,B,H,W]
    const float* K     = (const float*)d_in[2];  // K_matrix    [B,3,3]
    const float* M     = (const float*)d_in[3];  // M_matrix    [B,4,4]
    const float* diff  = (const float*)d_in[4];  // diff        [B,12]
    const float* trans = (const float*)d_in[5];  // trans_matrix[B,4,4]
    const float* feat  = (const float*)d_in[6];  // feature     [B,C,H,W]
    const int*   oW    = (const int*)  d_in[7];  // orig_W scalar
    const int*   oH    = (const int*)  d_in[8];  // orig_H scalar
    float* out = (float*)d_out;

    dim3 grid(HW_ / TILE, B_);   // 240 x 4 = 960 blocks
    points_kernel<<<grid, NT_, 0, stream>>>(dep, maskp, feat, diff, K, M, trans, oW, oH, out);
}